// Round 1
// baseline (448.281 us; speedup 1.0000x reference)
//
#include <hip/hip_runtime.h>
#include <math.h>

#define Hn 1024
#define En 1024
#define Ln 2048
#define Vn 50257

__device__ __forceinline__ float waveReduceSum(float v) {
#pragma unroll
    for (int off = 32; off > 0; off >>= 1)
        v += __shfl_down(v, off, 64);
    return v;
}

__device__ __forceinline__ float waveReduceMax(float v) {
#pragma unroll
    for (int off = 32; off > 0; off >>= 1)
        v = fmaxf(v, __shfl_down(v, off, 64));
    return v;
}

// ---------------- d[e] = dot(h_i, W_t[e,:]) + b_t[e] + emb[y, e] ----------------
// grid = 1024 blocks (one per e), block = 256
__global__ void k_d(const float* __restrict__ h_i, const float* __restrict__ W_t,
                    const float* __restrict__ b_t, const float* __restrict__ emb,
                    const int* __restrict__ y, float* __restrict__ d) {
    __shared__ float red[4];
    const int t = threadIdx.x;
    const int e = blockIdx.x;
    const float4 w = ((const float4*)(W_t + (size_t)e * Hn))[t];
    const float4 h = ((const float4*)h_i)[t];
    float acc = w.x * h.x + w.y * h.y + w.z * h.z + w.w * h.w;
    acc = waveReduceSum(acc);
    if ((t & 63) == 0) red[t >> 6] = acc;
    __syncthreads();
    if (t == 0) {
        float s = red[0] + red[1] + red[2] + red[3];
        d[e] = s + b_t[e] + emb[(size_t)y[0] * Hn + e];
    }
}

// ---------------- partial scores: part[p, l] = sum_{e in chunk p} d[e]*cnn_a[e,l] ----
// grid = (8, 16), block = 256.  blockIdx.x covers l (256 each), blockIdx.y covers e (64 each)
__global__ void k_scores(const float* __restrict__ d, const float* __restrict__ cnn_a,
                         float* __restrict__ part) {
    __shared__ float dsh[64];
    const int t = threadIdx.x;
    const int e0 = blockIdx.y * 64;
    if (t < 64) dsh[t] = d[e0 + t];
    __syncthreads();
    const int l = blockIdx.x * 256 + t;
    float acc = 0.f;
#pragma unroll 8
    for (int e = 0; e < 64; ++e)
        acc += dsh[e] * cnn_a[(size_t)(e0 + e) * Ln + l];
    part[(size_t)blockIdx.y * Ln + l] = acc;
}

// ---------------- softmax over L=2048 (also reduces the 16 partials) --------------
// grid = 1, block = 1024; each thread owns l = t and l = t+1024
__global__ void k_softmax(const float* __restrict__ part, float* __restrict__ a) {
    __shared__ float red[16];
    __shared__ float m_s, s_s;
    const int t = threadIdx.x;
    float v0 = 0.f, v1 = 0.f;
#pragma unroll
    for (int p = 0; p < 16; ++p) {
        v0 += part[(size_t)p * Ln + t];
        v1 += part[(size_t)p * Ln + t + 1024];
    }
    float m = fmaxf(v0, v1);
    m = waveReduceMax(m);
    if ((t & 63) == 0) red[t >> 6] = m;
    __syncthreads();
    if (t == 0) {
        float mm = red[0];
#pragma unroll
        for (int i = 1; i < 16; ++i) mm = fmaxf(mm, red[i]);
        m_s = mm;
    }
    __syncthreads();
    m = m_s;
    const float e0 = expf(v0 - m), e1 = expf(v1 - m);
    float s = e0 + e1;
    s = waveReduceSum(s);
    if ((t & 63) == 0) red[t >> 6] = s;
    __syncthreads();
    if (t == 0) {
        float ss = 0.f;
#pragma unroll
        for (int i = 0; i < 16; ++i) ss += red[i];
        s_s = ss;
    }
    __syncthreads();
    const float inv = 1.0f / s_s;
    a[t] = e0 * inv;
    a[t + 1024] = e1 * inv;
}

// ---------------- c[h] = dot(a, cnn_c[h,:]) ----------------
// grid = 1024, block = 256
__global__ void k_c(const float* __restrict__ a, const float* __restrict__ cnn_c,
                    float* __restrict__ c) {
    __shared__ float red[4];
    const int t = threadIdx.x;
    const int h = blockIdx.x;
    const float4* r4 = (const float4*)(cnn_c + (size_t)h * Ln);
    const float4* a4 = (const float4*)a;
    float acc = 0.f;
#pragma unroll
    for (int j = 0; j < 2; ++j) {
        const int idx = t + j * 256;
        const float4 w = r4[idx];
        const float4 av = a4[idx];
        acc += w.x * av.x + w.y * av.y + w.z * av.z + w.w * av.w;
    }
    acc = waveReduceSum(acc);
    if ((t & 63) == 0) red[t >> 6] = acc;
    __syncthreads();
    if (t == 0) c[h] = red[0] + red[1] + red[2] + red[3];
}

// ---------------- GRU row dots: gx[i]=dot(W_ih[i,:],[g;c])+b_ih[i]; gh[i]=dot(W_hh[i,:],h0)+b_hh[i]
// grid = 3072, block = 256
__global__ void k_gru(const float* __restrict__ emb, const int* __restrict__ y,
                      const float* __restrict__ c, const float* __restrict__ h0,
                      const float* __restrict__ W_ih, const float* __restrict__ W_hh,
                      const float* __restrict__ b_ih, const float* __restrict__ b_hh,
                      float* __restrict__ gx, float* __restrict__ gh) {
    __shared__ float redx[4], redh[4];
    const int t = threadIdx.x;
    const int i = blockIdx.x;
    const float* g = emb + (size_t)y[0] * Hn;
    const float4* wih = (const float4*)(W_ih + (size_t)i * (Hn + En));
    const float4* whh = (const float4*)(W_hh + (size_t)i * Hn);
    float accx, acch;
    {
        float4 w = wih[t];
        float4 xv = ((const float4*)g)[t];
        accx = w.x * xv.x + w.y * xv.y + w.z * xv.z + w.w * xv.w;
        w = wih[t + 256];
        xv = ((const float4*)c)[t];
        accx += w.x * xv.x + w.y * xv.y + w.z * xv.z + w.w * xv.w;
    }
    {
        const float4 w = whh[t];
        const float4 hv = ((const float4*)h0)[t];
        acch = w.x * hv.x + w.y * hv.y + w.z * hv.z + w.w * hv.w;
    }
    accx = waveReduceSum(accx);
    acch = waveReduceSum(acch);
    if ((t & 63) == 0) { redx[t >> 6] = accx; redh[t >> 6] = acch; }
    __syncthreads();
    if (t == 0) {
        gx[i] = redx[0] + redx[1] + redx[2] + redx[3] + b_ih[i];
        gh[i] = redh[0] + redh[1] + redh[2] + redh[3] + b_hh[i];
    }
}

// ---------------- gates -> h_new ----------------
// grid = 4, block = 256
__global__ void k_gates(const float* __restrict__ gx, const float* __restrict__ gh,
                        const float* __restrict__ h0, float* __restrict__ hn,
                        float* __restrict__ out_h) {
    const int i = blockIdx.x * 256 + threadIdx.x;
    const float r = 1.f / (1.f + expf(-(gx[i] + gh[i])));
    const float z = 1.f / (1.f + expf(-(gx[Hn + i] + gh[Hn + i])));
    const float n = tanhf(gx[2 * Hn + i] + r * gh[2 * Hn + i]);
    const float hv = (1.f - z) * n + z * h0[i];
    hn[i] = hv;
    out_h[i] = hv;
}

// ---------------- logits[v] = dot(W_o[v,:], h_new) + b_o[v] ----------------
// one wave per row; block = 256 (4 waves), grid = ceil(V/4)
__global__ __launch_bounds__(256) void k_logits(const float* __restrict__ W_o,
                                                const float* __restrict__ b_o,
                                                const float* __restrict__ hn,
                                                float* __restrict__ logits) {
    __shared__ float hsh[Hn];
    const int t = threadIdx.x;
    ((float4*)hsh)[t] = ((const float4*)hn)[t];
    __syncthreads();
    const int wid = t >> 6, lane = t & 63;
    const int v = blockIdx.x * 4 + wid;
    if (v >= Vn) return;
    const float4* row = (const float4*)(W_o + (size_t)v * Hn);
    const float4* h4 = (const float4*)hsh;
    float acc = 0.f;
#pragma unroll
    for (int j = 0; j < 4; ++j) {
        const float4 w = row[lane + j * 64];
        const float4 hv = h4[lane + j * 64];
        acc += w.x * hv.x + w.y * hv.y + w.z * hv.z + w.w * hv.w;
    }
    acc = waveReduceSum(acc);
    if (lane == 0) logits[v] = acc + b_o[v];
}

// ---------------- in-place log_softmax over V on d_out[0..V) ----------------
// grid = 1, block = 1024
__global__ void k_logsoftmax(float* __restrict__ out) {
    __shared__ float red[16];
    __shared__ float m_s, s_s;
    const int t = threadIdx.x;
    float m = -INFINITY;
    for (int v = t; v < Vn; v += 1024) m = fmaxf(m, out[v]);
    m = waveReduceMax(m);
    if ((t & 63) == 0) red[t >> 6] = m;
    __syncthreads();
    if (t == 0) {
        float mm = red[0];
#pragma unroll
        for (int i = 1; i < 16; ++i) mm = fmaxf(mm, red[i]);
        m_s = mm;
    }
    __syncthreads();
    m = m_s;
    float s = 0.f;
    for (int v = t; v < Vn; v += 1024) s += expf(out[v] - m);
    s = waveReduceSum(s);
    if ((t & 63) == 0) red[t >> 6] = s;
    __syncthreads();
    if (t == 0) {
        float ss = 0.f;
#pragma unroll
        for (int i = 0; i < 16; ++i) ss += red[i];
        s_s = ss;
    }
    __syncthreads();
    const float lse = m + logf(s_s);
    for (int v = t; v < Vn; v += 1024) out[v] = out[v] - lse;
}

extern "C" void kernel_launch(void* const* d_in, const int* in_sizes, int n_in,
                              void* d_out, int out_size, void* d_ws, size_t ws_size,
                              hipStream_t stream) {
    const int*   y     = (const int*)d_in[0];
    const float* h_i   = (const float*)d_in[1];
    const float* cnn_a = (const float*)d_in[2];
    const float* cnn_c = (const float*)d_in[3];
    const float* emb   = (const float*)d_in[4];
    const float* W_t   = (const float*)d_in[5];
    const float* b_t   = (const float*)d_in[6];
    const float* W_ih  = (const float*)d_in[7];
    const float* W_hh  = (const float*)d_in[8];
    const float* b_ih  = (const float*)d_in[9];
    const float* b_hh  = (const float*)d_in[10];
    const float* W_o   = (const float*)d_in[11];
    const float* b_o   = (const float*)d_in[12];
    float* out = (float*)d_out;

    float* ws    = (float*)d_ws;
    float* d_vec = ws;                 // 1024
    float* part  = d_vec + 1024;       // 16*2048 = 32768
    float* a_vec = part + 16 * Ln;     // 2048
    float* c_vec = a_vec + Ln;         // 1024
    float* gx    = c_vec + Hn;         // 3072
    float* gh    = gx + 3 * Hn;        // 3072
    float* hn    = gh + 3 * Hn;        // 1024
    // total: 44032 floats = 172 KiB of d_ws

    k_d<<<dim3(En), dim3(256), 0, stream>>>(h_i, W_t, b_t, emb, y, d_vec);
    k_scores<<<dim3(8, 16), dim3(256), 0, stream>>>(d_vec, cnn_a, part);
    k_softmax<<<dim3(1), dim3(1024), 0, stream>>>(part, a_vec);
    k_c<<<dim3(Hn), dim3(256), 0, stream>>>(a_vec, cnn_c, c_vec);
    k_gru<<<dim3(3 * Hn), dim3(256), 0, stream>>>(emb, y, c_vec, h_i, W_ih, W_hh,
                                                  b_ih, b_hh, gx, gh);
    k_gates<<<dim3(4), dim3(256), 0, stream>>>(gx, gh, h_i, hn, out + Vn);
    k_logits<<<dim3((Vn + 3) / 4), dim3(256), 0, stream>>>(W_o, b_o, hn, out);
    k_logsoftmax<<<dim3(1), dim3(1024), 0, stream>>>(out);
}